// Round 4
// baseline (145.736 us; speedup 1.0000x reference)
//
#include <hip/hip_runtime.h>
#include <stdint.h>

#define NROWS 8192
#define NN 4096
#define KK 64
#define NBUCK 8192
#define BB_CAP 512

typedef unsigned long long u64;

__global__ __launch_bounds__(256) void atom_topk_kernel(
    const float* __restrict__ x, const float* __restrict__ thrp,
    float* __restrict__ feat, float* __restrict__ idxout,
    float* __restrict__ valid)
{
  __shared__ uint32_t hist[NBUCK];
  __shared__ uint32_t chunkSum[256];
  __shared__ u64 sel[KK];        // definite winners (bucket > b*), unordered
  __shared__ u64 bb[BB_CAP];     // boundary-bucket candidates, unordered
  __shared__ uint32_t bm[NN / 32];
  __shared__ uint32_t sNsel, sNbb, sB;

  const int t = threadIdx.x;
  const int row = blockIdx.x;
  const float thr = thrp[0];

  // ---- zero LDS ----
  {
    uint4* h4 = (uint4*)hist;
    #pragma unroll
    for (int i = 0; i < NBUCK / 4 / 256; ++i) h4[i * 256 + t] = make_uint4(0, 0, 0, 0);
    if (t < NN / 32) bm[t] = 0;
    if (t < KK) sel[t] = 0;
    if (t == 0) { sNsel = 0; sNbb = 0; sB = 0; }
  }

  // ---- load 16 elements / thread (coalesced float4) ----
  float4 vv[4];
  const float4* x4 = (const float4*)(x + (size_t)row * NN);
  #pragma unroll
  for (int c = 0; c < 4; ++c) vv[c] = x4[c * 256 + t];

  // ---- valid mask output (f32 1.0/0.0) ----
  {
    float4* vout = (float4*)(valid + (size_t)row * NN);
    #pragma unroll
    for (int c = 0; c < 4; ++c) {
      float4 m;
      m.x = vv[c].x >= thr ? 1.0f : 0.0f;
      m.y = vv[c].y >= thr ? 1.0f : 0.0f;
      m.z = vv[c].z >= thr ? 1.0f : 0.0f;
      m.w = vv[c].w >= thr ? 1.0f : 0.0f;
      vout[c * 256 + t] = m;
    }
  }

  __syncthreads();  // hist zeroed, counters zeroed

  // ---- histogram of candidates (positive floats: bit order == value order) ----
  #pragma unroll
  for (int c = 0; c < 4; ++c) {
    const float vals[4] = {vv[c].x, vv[c].y, vv[c].z, vv[c].w};
    #pragma unroll
    for (int j = 0; j < 4; ++j) {
      if (vals[j] >= thr) atomicAdd(&hist[__float_as_uint(vals[j]) >> 18], 1u);
    }
  }
  __syncthreads();

  // ---- per-thread sum of its 32 buckets ----
  {
    const uint4* h4 = (const uint4*)hist;
    uint32_t s = 0;
    #pragma unroll
    for (int i = 0; i < 8; ++i) {
      uint4 u = h4[t * 8 + i];
      s += u.x + u.y + u.z + u.w;
    }
    chunkSum[t] = s;
  }
  __syncthreads();

  // ---- thread 0: serial scan, high->low, find boundary bucket b* ----
  if (t == 0) {
    uint32_t acc = 0;  // count of candidates in buckets strictly above current position
    int C = 0;
    for (int c = 255; c >= 0; --c) {
      uint32_t cs = chunkSum[c];
      if (acc + cs >= (uint32_t)KK) { C = c; break; }
      acc += cs;
    }
    uint32_t bstar = 0;
    for (int b = 31; b >= 0; --b) {
      uint32_t h = hist[C * 32 + b];
      if (acc + h >= (uint32_t)KK) { bstar = (uint32_t)(C * 32 + b); break; }
      acc += h;
    }
    sB = bstar;
  }
  __syncthreads();

  const uint32_t bstar = sB;

  // ---- collect: definite winners (bucket > b*) -> sel; boundary bucket -> bb ----
  #pragma unroll
  for (int c = 0; c < 4; ++c) {
    const float vals[4] = {vv[c].x, vv[c].y, vv[c].z, vv[c].w};
    #pragma unroll
    for (int j = 0; j < 4; ++j) {
      const bool cand = vals[j] >= thr;
      const uint32_t bits = cand ? __float_as_uint(vals[j]) : 0u;
      const uint32_t bucket = bits >> 18;
      const int e = (c * 256 + t) * 4 + j;
      const u64 key = ((u64)bits << 12) | (u64)(4095 - e);  // unique; value desc, then idx asc
      if (cand && bucket > bstar) {
        uint32_t p = atomicAdd(&sNsel, 1u);
        if (p < KK) sel[p] = key;
      } else if (cand && bucket == bstar) {
        uint32_t p = atomicAdd(&sNbb, 1u);
        if (p < BB_CAP) bb[p] = key;
      }
    }
  }
  __syncthreads();

  // ---- wave 0: rank-by-counting slot assignment (no shuffles, no sort network) ----
  if (t < 64) {
    const int nGT = (int)min(sNsel, (uint32_t)KK);
    const int r = KK - nGT;                      // >= 1 when scan is correct
    const int nbb = (int)min(sNbb, (uint32_t)BB_CAP);

    // definite winners: rank among themselves = final slot
    if (t < nGT) {
      const u64 k = sel[t];
      int rank = 0;
      for (int j = 0; j < nGT; ++j) rank += (sel[j] > k) ? 1 : 0;
      const int idx = 4095 - (int)(k & 0xFFFull);
      idxout[(size_t)row * KK + rank] = (float)idx;
      atomicOr(&bm[(uint32_t)idx >> 5], 1u << (idx & 31));
    }
    // boundary bucket: keep the r highest-ranked keys; slot = nGT + rank
    for (int i = t; i < nbb; i += 64) {
      const u64 k = bb[i];
      int rank = 0;
      for (int j = 0; j < nbb; ++j) rank += (bb[j] > k) ? 1 : 0;
      if (rank < r) {
        const int idx = 4095 - (int)(k & 0xFFFull);
        idxout[(size_t)row * KK + nGT + rank] = (float)idx;
        atomicOr(&bm[(uint32_t)idx >> 5], 1u << (idx & 31));
      }
    }
  }
  __syncthreads();

  // ---- feat output: one-hot from bitmask (f32) ----
  {
    float4* fout = (float4*)(feat + (size_t)row * NN);
    #pragma unroll
    for (int c = 0; c < 4; ++c) {
      const int e0 = (c * 256 + t) * 4;
      const uint32_t w = bm[e0 >> 5] >> (e0 & 31);
      float4 f;
      f.x = (w & 1u) ? 1.0f : 0.0f;
      f.y = (w & 2u) ? 1.0f : 0.0f;
      f.z = (w & 4u) ? 1.0f : 0.0f;
      f.w = (w & 8u) ? 1.0f : 0.0f;
      fout[c * 256 + t] = f;
    }
  }
}

extern "C" void kernel_launch(void* const* d_in, const int* in_sizes, int n_in,
                              void* d_out, int out_size, void* d_ws, size_t ws_size,
                              hipStream_t stream) {
  const float* x = (const float*)d_in[0];
  const float* thr = (const float*)d_in[1];
  float* out = (float*)d_out;
  float* feat = out;                                   // [16,512,4096] f32
  float* idxout = out + (size_t)NROWS * NN;            // [16,512,64]  f32 (index values)
  float* valid = idxout + (size_t)NROWS * KK;          // [16,512,4096] f32
  atom_topk_kernel<<<NROWS, 256, 0, stream>>>(x, thr, feat, idxout, valid);
}

// Round 5
// 83.094 us; speedup vs baseline: 1.7539x; 1.7539x over previous
//
#include <hip/hip_runtime.h>
#include <stdint.h>

#define NROWS 8192
#define NN 4096
#define KK 64
#define SHIFT 20
#define NBUCK 2048      // positive-float bits >> 20
#define NCHUNK 256      // 8 buckets per chunk
#define BB_CAP 512

typedef unsigned long long u64;

__global__ __launch_bounds__(256) void atom_topk_kernel(
    const float* __restrict__ x, const float* __restrict__ thrp,
    float* __restrict__ feat, float* __restrict__ idxout,
    float* __restrict__ valid)
{
  __shared__ uint32_t hist[NBUCK];
  __shared__ uint32_t sfx[NCHUNK];   // chunk sums -> suffix sums (in-place)
  __shared__ u64 sel[KK];            // definite winners (bucket > b*), unordered
  __shared__ u64 bb[BB_CAP];         // boundary-bucket candidates, unordered
  __shared__ uint32_t bm[NN / 32];
  __shared__ uint32_t sNsel, sNbb, sB, sC, sAcc;

  const int t = threadIdx.x;
  const int row = blockIdx.x;
  const float thr = thrp[0];

  // ---- zero LDS ----
  {
    uint4* h4 = (uint4*)hist;        // 512 uint4
    h4[t] = make_uint4(0, 0, 0, 0);
    h4[t + 256] = make_uint4(0, 0, 0, 0);
    if (t < NN / 32) bm[t] = 0;
    if (t < KK) sel[t] = 0;
    if (t == 0) { sNsel = 0; sNbb = 0; sB = 0; sC = 0; sAcc = 0; }
  }

  // ---- load 16 elements / thread (coalesced float4) ----
  float4 vv[4];
  const float4* x4 = (const float4*)(x + (size_t)row * NN);
  #pragma unroll
  for (int c = 0; c < 4; ++c) vv[c] = x4[c * 256 + t];

  // ---- valid mask output (f32 1.0/0.0) ----
  {
    float4* vout = (float4*)(valid + (size_t)row * NN);
    #pragma unroll
    for (int c = 0; c < 4; ++c) {
      float4 m;
      m.x = vv[c].x >= thr ? 1.0f : 0.0f;
      m.y = vv[c].y >= thr ? 1.0f : 0.0f;
      m.z = vv[c].z >= thr ? 1.0f : 0.0f;
      m.w = vv[c].w >= thr ? 1.0f : 0.0f;
      vout[c * 256 + t] = m;
    }
  }

  __syncthreads();  // LDS zeroed

  // ---- histogram of candidates (positive floats: bit order == value order) ----
  #pragma unroll
  for (int c = 0; c < 4; ++c) {
    const float vals[4] = {vv[c].x, vv[c].y, vv[c].z, vv[c].w};
    #pragma unroll
    for (int j = 0; j < 4; ++j) {
      if (vals[j] >= thr) atomicAdd(&hist[__float_as_uint(vals[j]) >> SHIFT], 1u);
    }
  }
  __syncthreads();

  // ---- chunk sums (8 buckets per chunk, 2 x b128 per thread) ----
  {
    const uint4* h4 = (const uint4*)hist;
    uint4 a = h4[t * 2];
    uint4 b = h4[t * 2 + 1];
    sfx[t] = a.x + a.y + a.z + a.w + b.x + b.y + b.z + b.w;
  }
  __syncthreads();

  // ---- in-place Hillis-Steele suffix sum over 256 chunks (all threads) ----
  #pragma unroll
  for (int d = 1; d < NCHUNK; d <<= 1) {
    uint32_t v = sfx[t] + ((t + d < NCHUNK) ? sfx[t + d] : 0u);
    __syncthreads();
    sfx[t] = v;
    __syncthreads();
  }

  // ---- detect boundary chunk: largest c with suffix[c] >= KK (unique) ----
  {
    uint32_t s = sfx[t];
    uint32_t nb = (t < NCHUNK - 1) ? sfx[t + 1] : 0u;
    if (s >= (uint32_t)KK && nb < (uint32_t)KK) { sC = (uint32_t)t; sAcc = nb; }
  }
  __syncthreads();

  // ---- thread 0: bucket-level walk inside the single boundary chunk (8 iters) ----
  if (t == 0) {
    uint32_t acc = sAcc;
    const int base = (int)sC * 8;
    uint32_t bstar = 0;
    for (int b = 7; b >= 0; --b) {
      uint32_t h = hist[base + b];
      if (acc + h >= (uint32_t)KK) { bstar = (uint32_t)(base + b); break; }
      acc += h;
    }
    sB = bstar;
  }
  __syncthreads();

  const uint32_t bstar = sB;

  // ---- collect: definite winners (bucket > b*) -> sel; boundary bucket -> bb ----
  #pragma unroll
  for (int c = 0; c < 4; ++c) {
    const float vals[4] = {vv[c].x, vv[c].y, vv[c].z, vv[c].w};
    #pragma unroll
    for (int j = 0; j < 4; ++j) {
      const bool cand = vals[j] >= thr;
      const uint32_t bits = cand ? __float_as_uint(vals[j]) : 0u;
      const uint32_t bucket = bits >> SHIFT;
      const int e = (c * 256 + t) * 4 + j;
      const u64 key = ((u64)bits << 12) | (u64)(4095 - e);  // unique; value desc, then idx asc
      if (cand && bucket > bstar) {
        uint32_t p = atomicAdd(&sNsel, 1u);
        if (p < KK) sel[p] = key;
      } else if (cand && bucket == bstar) {
        uint32_t p = atomicAdd(&sNbb, 1u);
        if (p < BB_CAP) bb[p] = key;
      }
    }
  }
  __syncthreads();

  // ---- wave 0: rank-by-counting slot assignment (no shuffles) ----
  if (t < 64) {
    const int nGT = (int)min(sNsel, (uint32_t)KK);
    const int r = KK - nGT;
    const int nbb = (int)min(sNbb, (uint32_t)BB_CAP);

    // definite winners: rank among themselves = final slot
    if (t < nGT) {
      const u64 k = sel[t];
      int rank = 0;
      for (int j = 0; j < nGT; ++j) rank += (sel[j] > k) ? 1 : 0;
      const int idx = 4095 - (int)(k & 0xFFFull);
      idxout[(size_t)row * KK + rank] = (float)idx;
      atomicOr(&bm[(uint32_t)idx >> 5], 1u << (idx & 31));
    }
    // boundary bucket: keep the r highest-ranked keys; slot = nGT + rank
    for (int i = t; i < nbb; i += 64) {
      const u64 k = bb[i];
      int rank = 0;
      for (int j = 0; j < nbb; ++j) rank += (bb[j] > k) ? 1 : 0;
      if (rank < r) {
        const int idx = 4095 - (int)(k & 0xFFFull);
        idxout[(size_t)row * KK + nGT + rank] = (float)idx;
        atomicOr(&bm[(uint32_t)idx >> 5], 1u << (idx & 31));
      }
    }
  }
  __syncthreads();

  // ---- feat output: one-hot from bitmask (f32) ----
  {
    float4* fout = (float4*)(feat + (size_t)row * NN);
    #pragma unroll
    for (int c = 0; c < 4; ++c) {
      const int e0 = (c * 256 + t) * 4;
      const uint32_t w = bm[e0 >> 5] >> (e0 & 31);
      float4 f;
      f.x = (w & 1u) ? 1.0f : 0.0f;
      f.y = (w & 2u) ? 1.0f : 0.0f;
      f.z = (w & 4u) ? 1.0f : 0.0f;
      f.w = (w & 8u) ? 1.0f : 0.0f;
      fout[c * 256 + t] = f;
    }
  }
}

extern "C" void kernel_launch(void* const* d_in, const int* in_sizes, int n_in,
                              void* d_out, int out_size, void* d_ws, size_t ws_size,
                              hipStream_t stream) {
  const float* x = (const float*)d_in[0];
  const float* thr = (const float*)d_in[1];
  float* out = (float*)d_out;
  float* feat = out;                                   // [16,512,4096] f32
  float* idxout = out + (size_t)NROWS * NN;            // [16,512,64]  f32 (index values)
  float* valid = idxout + (size_t)NROWS * KK;          // [16,512,4096] f32
  atom_topk_kernel<<<NROWS, 256, 0, stream>>>(x, thr, feat, idxout, valid);
}

// Round 6
// 62.100 us; speedup vs baseline: 2.3468x; 1.3381x over previous
//
#include <hip/hip_runtime.h>
#include <stdint.h>

#define NROWS 8192
#define NN 4096
#define KK 64
#define SHIFT 20
#define NBUCK 2048      // positive-float bits >> 20
#define NCHUNK 256      // 8 buckets per chunk
#define BB_CAP 512

typedef unsigned long long u64;
typedef float f4v __attribute__((ext_vector_type(4)));

__global__ __launch_bounds__(256) void atom_topk_kernel(
    const float* __restrict__ x, const float* __restrict__ thrp,
    float* __restrict__ feat, float* __restrict__ idxout,
    float* __restrict__ valid)
{
  __shared__ uint32_t hist[NBUCK];
  __shared__ uint32_t sfxA[NCHUNK];
  __shared__ uint32_t sfxB[NCHUNK];
  __shared__ u64 sel[KK];            // definite winners (bucket > b*), unordered
  __shared__ u64 bb[BB_CAP];         // boundary-bucket candidates, unordered
  __shared__ uint32_t bm[NN / 32];
  __shared__ uint32_t sNsel, sNbb, sB, sC, sAcc;

  const int t = threadIdx.x;
  const int row = blockIdx.x;
  const float thr = thrp[0];

  // ---- zero LDS ----
  {
    uint4* h4 = (uint4*)hist;        // 512 uint4
    h4[t] = make_uint4(0, 0, 0, 0);
    h4[t + 256] = make_uint4(0, 0, 0, 0);
    if (t < NN / 32) bm[t] = 0;
    if (t < KK) sel[t] = 0;
    if (t == 0) { sNsel = 0; sNbb = 0; sB = 0; sC = 0; sAcc = 0; }
  }

  // ---- load 16 elements / thread (coalesced float4) ----
  float4 vv[4];
  const float4* x4 = (const float4*)(x + (size_t)row * NN);
  #pragma unroll
  for (int c = 0; c < 4; ++c) vv[c] = x4[c * 256 + t];

  // ---- valid mask output (f32 1.0/0.0, nontemporal) ----
  {
    f4v* vout = (f4v*)(valid + (size_t)row * NN);
    #pragma unroll
    for (int c = 0; c < 4; ++c) {
      f4v m;
      m.x = vv[c].x >= thr ? 1.0f : 0.0f;
      m.y = vv[c].y >= thr ? 1.0f : 0.0f;
      m.z = vv[c].z >= thr ? 1.0f : 0.0f;
      m.w = vv[c].w >= thr ? 1.0f : 0.0f;
      __builtin_nontemporal_store(m, vout + c * 256 + t);
    }
  }

  __syncthreads();  // LDS zeroed

  // ---- histogram of candidates (positive floats: bit order == value order) ----
  #pragma unroll
  for (int c = 0; c < 4; ++c) {
    const float vals[4] = {vv[c].x, vv[c].y, vv[c].z, vv[c].w};
    #pragma unroll
    for (int j = 0; j < 4; ++j) {
      if (vals[j] >= thr) atomicAdd(&hist[__float_as_uint(vals[j]) >> SHIFT], 1u);
    }
  }
  __syncthreads();

  // ---- chunk sums (8 buckets per chunk, 2 x b128 per thread) ----
  {
    const uint4* h4 = (const uint4*)hist;
    uint4 a = h4[t * 2];
    uint4 b = h4[t * 2 + 1];
    sfxA[t] = a.x + a.y + a.z + a.w + b.x + b.y + b.z + b.w;
  }
  __syncthreads();

  // ---- ping-pong Hillis-Steele suffix sum over 256 chunks (8 barriers) ----
  {
    uint32_t* src = sfxA;
    uint32_t* dst = sfxB;
    #pragma unroll
    for (int d = 1; d < NCHUNK; d <<= 1) {
      dst[t] = src[t] + ((t + d < NCHUNK) ? src[t + d] : 0u);
      __syncthreads();
      uint32_t* tmp = src; src = dst; dst = tmp;
    }
    // result is in src (== sfxA after 8 swaps)
    uint32_t s = src[t];
    uint32_t nb = (t < NCHUNK - 1) ? src[t + 1] : 0u;
    if (s >= (uint32_t)KK && nb < (uint32_t)KK) { sC = (uint32_t)t; sAcc = nb; }
  }
  __syncthreads();

  // ---- thread 0: bucket-level walk inside the single boundary chunk (8 iters) ----
  if (t == 0) {
    uint32_t acc = sAcc;
    const int base = (int)sC * 8;
    uint32_t bstar = 0;
    for (int b = 7; b >= 0; --b) {
      uint32_t h = hist[base + b];
      if (acc + h >= (uint32_t)KK) { bstar = (uint32_t)(base + b); break; }
      acc += h;
    }
    sB = bstar;
  }
  __syncthreads();

  const uint32_t bstar = sB;

  // ---- collect: definite winners (bucket > b*) -> sel; boundary bucket -> bb ----
  #pragma unroll
  for (int c = 0; c < 4; ++c) {
    const float vals[4] = {vv[c].x, vv[c].y, vv[c].z, vv[c].w};
    #pragma unroll
    for (int j = 0; j < 4; ++j) {
      const bool cand = vals[j] >= thr;
      const uint32_t bits = cand ? __float_as_uint(vals[j]) : 0u;
      const uint32_t bucket = bits >> SHIFT;
      const int e = (c * 256 + t) * 4 + j;
      const u64 key = ((u64)bits << 12) | (u64)(4095 - e);  // unique; value desc, then idx asc
      if (cand && bucket > bstar) {
        uint32_t p = atomicAdd(&sNsel, 1u);
        if (p < KK) sel[p] = key;
      } else if (cand && bucket == bstar) {
        uint32_t p = atomicAdd(&sNbb, 1u);
        if (p < BB_CAP) bb[p] = key;
      }
    }
  }
  __syncthreads();

  // ---- wave 0: rank-by-counting slot assignment (no shuffles) ----
  if (t < 64) {
    const int nGT = (int)min(sNsel, (uint32_t)KK);
    const int r = KK - nGT;
    const int nbb = (int)min(sNbb, (uint32_t)BB_CAP);

    // definite winners: rank among themselves = final slot
    if (t < nGT) {
      const u64 k = sel[t];
      int rank = 0;
      for (int j = 0; j < nGT; ++j) rank += (sel[j] > k) ? 1 : 0;
      const int idx = 4095 - (int)(k & 0xFFFull);
      __builtin_nontemporal_store((float)idx, idxout + (size_t)row * KK + rank);
      atomicOr(&bm[(uint32_t)idx >> 5], 1u << (idx & 31));
    }
    // boundary bucket: keep the r highest-ranked keys; slot = nGT + rank
    for (int i = t; i < nbb; i += 64) {
      const u64 k = bb[i];
      int rank = 0;
      for (int j = 0; j < nbb; ++j) rank += (bb[j] > k) ? 1 : 0;
      if (rank < r) {
        const int idx = 4095 - (int)(k & 0xFFFull);
        __builtin_nontemporal_store((float)idx, idxout + (size_t)row * KK + nGT + rank);
        atomicOr(&bm[(uint32_t)idx >> 5], 1u << (idx & 31));
      }
    }
  }
  __syncthreads();

  // ---- feat output: one-hot from bitmask (f32, nontemporal) ----
  {
    f4v* fout = (f4v*)(feat + (size_t)row * NN);
    #pragma unroll
    for (int c = 0; c < 4; ++c) {
      const int e0 = (c * 256 + t) * 4;
      const uint32_t w = bm[e0 >> 5] >> (e0 & 31);
      f4v f;
      f.x = (w & 1u) ? 1.0f : 0.0f;
      f.y = (w & 2u) ? 1.0f : 0.0f;
      f.z = (w & 4u) ? 1.0f : 0.0f;
      f.w = (w & 8u) ? 1.0f : 0.0f;
      __builtin_nontemporal_store(f, fout + c * 256 + t);
    }
  }
}

extern "C" void kernel_launch(void* const* d_in, const int* in_sizes, int n_in,
                              void* d_out, int out_size, void* d_ws, size_t ws_size,
                              hipStream_t stream) {
  const float* x = (const float*)d_in[0];
  const float* thr = (const float*)d_in[1];
  float* out = (float*)d_out;
  float* feat = out;                                   // [16,512,4096] f32
  float* idxout = out + (size_t)NROWS * NN;            // [16,512,64]  f32 (index values)
  float* valid = idxout + (size_t)NROWS * KK;          // [16,512,4096] f32
  atom_topk_kernel<<<NROWS, 256, 0, stream>>>(x, thr, feat, idxout, valid);
}